// Round 3
// baseline (1083.411 us; speedup 1.0000x reference)
//
#include <hip/hip_runtime.h>
#include <hip/hip_cooperative_groups.h>
#include <float.h>

namespace cgr = cooperative_groups;

#define NN 16384
#define DD 128
#define KK 64
#define N_ITERS 10
#define NCHK 256          // blocks = row chunks
#define RPB 64            // rows per block
#define CSTR 132          // padded centroid LDS stride (floats)
#define EPSN 1e-12f
#define TOL2 1e-8f        // (1e-4)^2
#define MOM 0.9f
#define MOM1 0.1f

__device__ __forceinline__ bool gt_pair(float v, int i, float w, int j) {
  return (v > w) || (v == w && i < j);
}

__global__ __launch_bounds__(256, 1) void k_mega(
    const float* __restrict__ E, const float* __restrict__ C0,
    float* __restrict__ out,
    float* __restrict__ cb0, float* __restrict__ cb1,
    float* __restrict__ updb, float* __restrict__ n2b,
    float* __restrict__ partial, int* __restrict__ pcount,
    int* __restrict__ negidx, float* __restrict__ simT,
    int* __restrict__ colti) {
  cgr::grid_group grid = cgr::this_grid();
  const int t = threadIdx.x;
  const int bid = blockIdx.x;

  __shared__ float csp[KK * CSTR];    // normalized centroids (padded)
  __shared__ float smem2[KK * DD];    // acc / sim tile [64][65]
  __shared__ float rows[RPB * DD];    // raw rows, resident all iterations
  __shared__ float cinv[KK];
  __shared__ int lab[RPB];
  __shared__ int s_sel;
  __shared__ int ci[2];
  __shared__ float red[2];
  __shared__ float cs1[256], cs2[256];
  __shared__ int ct1[256], ct2[256];

  // ---- raw rows into LDS once (used by segment accumulation)
  {
    const float4* src = (const float4*)(E + (size_t)bid * RPB * DD);
    float4* dst = (float4*)rows;
    for (int q = t; q < RPB * DD / 4; q += 256) dst[q] = src[q];
  }
  // ---- own row into registers, normalized (same fp ops/order as before)
  const int row = bid * RPB + (t >> 2);
  const int cg4 = t & 3;
  const int rloc = t >> 2;
  float4 rv[32];
  {
    const float4* rp = (const float4*)(E + (size_t)row * DD);
    float s = 0.f;
#pragma unroll
    for (int q = 0; q < 32; ++q) {
      float4 v = rp[q];
      s += v.x * v.x + v.y * v.y + v.z * v.z + v.w * v.w;
      rv[q] = v;
    }
    float inv = 1.0f / fmaxf(sqrtf(s), EPSN);
#pragma unroll
    for (int q = 0; q < 32; ++q) {
      rv[q].x *= inv; rv[q].y *= inv; rv[q].z *= inv; rv[q].w *= inv;
    }
  }

  for (int it = 0; it <= N_ITERS; ++it) {
    const int is_final = (it == N_ITERS);
    const float* cprev = (it == 0) ? C0 : ((it & 1) ? cb0 : cb1);
    float* ccur = (it & 1) ? cb1 : cb0;

    // --- convergence selection (sticky by construction)
    if (t < 64) {
      bool ok = (it == 0) ? true : (n2b[t] < TOL2);
      unsigned long long mask = __ballot(ok);
      if (t == 0) s_sel = (it == 0) ? 1 : ((mask == ~0ull) ? 1 : 0);
    }
    __syncthreads();
    const int takeC = s_sel;

    // --- stage selected raw centroids; block 0 materializes for reduce/output
    for (int e = t; e < KK * DD; e += 256) {
      float v = takeC ? cprev[e] : updb[e];
      csp[(e >> 7) * CSTR + (e & 127)] = v;
      if (bid == 0) {
        if (is_final) out[e] = v;
        else ccur[e] = v;
      }
    }
    __syncthreads();
    if (t < KK) {
      const float4* cm = (const float4*)(csp + t * CSTR);
      float s = 0.f;
#pragma unroll
      for (int q = 0; q < 32; ++q) {
        float4 v = cm[q];
        s += v.x * v.x + v.y * v.y + v.z * v.z + v.w * v.w;
      }
      cinv[t] = 1.0f / fmaxf(sqrtf(s), EPSN);
    }
    __syncthreads();
    for (int e = t; e < KK * DD; e += 256)
      csp[(e >> 7) * CSTR + (e & 127)] *= cinv[e >> 7];
    __syncthreads();

    // --- sim: 4 lanes/row x 16 centroids each, m interleaved
    float b1 = -3.0e38f, b2 = -3.0e38f;
    int i1 = 0, i2 = 0;
#pragma unroll 4
    for (int mm = 0; mm < 16; ++mm) {
      const int m = mm * 4 + cg4;
      const float4* cp = (const float4*)(csp + m * CSTR);
      float a = 0.f;
#pragma unroll
      for (int q = 0; q < 32; ++q) {
        float4 cv = cp[q];
        a += rv[q].x * cv.x + rv[q].y * cv.y + rv[q].z * cv.z + rv[q].w * cv.w;
      }
      if (is_final) smem2[rloc * 65 + m] = a;
      if (a > b1) { b2 = b1; i2 = i1; b1 = a; i1 = m; }
      else if (a > b2) { b2 = a; i2 = m; }
    }
    // merge top-2 across the 4 lanes of this row
#pragma unroll
    for (int off = 1; off < 4; off <<= 1) {
      float w1 = __shfl_xor(b1, off);
      float w2 = __shfl_xor(b2, off);
      int j1 = __shfl_xor(i1, off);
      int j2 = __shfl_xor(i2, off);
      float v1, v2f; int ni1, ni2;
      if (gt_pair(b1, i1, w1, j1)) {
        v1 = b1; ni1 = i1;
        if (gt_pair(b2, i2, w1, j1)) { v2f = b2; ni2 = i2; }
        else { v2f = w1; ni2 = j1; }
      } else {
        v1 = w1; ni1 = j1;
        if (gt_pair(b1, i1, w2, j2)) { v2f = b1; ni2 = i1; }
        else { v2f = w2; ni2 = j2; }
      }
      b1 = v1; i1 = ni1; b2 = v2f; i2 = ni2;
    }

    if (!is_final) {
      if (cg4 == 0) lab[rloc] = i1;
      __syncthreads();
      for (int e = t; e < KK * DD; e += 256) smem2[e] = 0.f;
      __syncthreads();
      // deterministic segment accumulation from LDS rows (ascending row order)
      if (t < 128) {
#pragma unroll 4
        for (int r = 0; r < RPB; ++r)
          smem2[lab[r] * DD + t] += rows[r * DD + t];
      } else if (t < 192) {
        const int m = t - 128;
        int c = 0;
#pragma unroll
        for (int r = 0; r < RPB; ++r) c += (lab[r] == m) ? 1 : 0;
        pcount[bid * KK + m] = c;
      }
      __syncthreads();
      for (int e = t; e < KK * DD; e += 256)
        partial[(size_t)bid * (KK * DD) + e] = smem2[e];
      grid.sync();

      // --- reduce (blocks 0..63), identical math/order to round-2 k_reduce
      if (bid < KK) {
        const int m = bid;
        float s = 0.f;
        int cp = 0;
        if (t < 128) {
#pragma unroll 8
          for (int ch = 0; ch < NCHK; ++ch)
            s += partial[(size_t)ch * (KK * DD) + m * DD + t];
          cp = pcount[t * KK + m] + pcount[(t + 128) * KK + m];
        }
#pragma unroll
        for (int off = 1; off < 64; off <<= 1) cp += __shfl_xor(cp, off);
        if (t < 128 && (t & 63) == 0) ci[t >> 6] = cp;
        __syncthreads();
        const int cnt = ci[0] + ci[1];
        if (t < 128) {
          float cv = ccur[m * DD + t];
          float mean = (cnt > 0) ? (s / fmaxf((float)cnt, 1.0f)) : cv;
          float u = MOM1 * cv + MOM * mean;
          updb[m * DD + t] = u;
          float diff = cv - u;
          float ss = diff * diff;
#pragma unroll
          for (int o = 32; o > 0; o >>= 1) ss += __shfl_down(ss, o);
          if ((t & 63) == 0) red[t >> 6] = ss;
        }
        __syncthreads();
        if (t == 0) n2b[m] = red[0] + red[1];
      }
      grid.sync();
    } else {
      // --- final: negidx + transposed coalesced simT write
      if (cg4 == 0) negidx[row] = i2;
      __syncthreads();
      const int mT = t >> 2;
      const int rc = t & 3;
#pragma unroll
      for (int i = 0; i < 4; ++i) {
        const int r0 = rc * 16 + i * 4;
        float4 vv;
        vv.x = smem2[(r0 + 0) * 65 + mT];
        vv.y = smem2[(r0 + 1) * 65 + mT];
        vv.z = smem2[(r0 + 2) * 65 + mT];
        vv.w = smem2[(r0 + 3) * 65 + mT];
        *(float4*)&simT[(size_t)mT * NN + bid * RPB + r0] = vv;
      }
    }
  }

  grid.sync();

  // --- per-centroid-column top-2 rows of simT (blocks 0..63)
  if (bid < KK) {
    const int m = bid;
    float b1 = -3.0e38f, b2 = -3.0e38f;
    int i1 = -1, i2 = -1;
    for (int j = t; j < NN; j += 256) {
      float v = simT[(size_t)m * NN + j];
      if (v > b1) { b2 = b1; i2 = i1; b1 = v; i1 = j; }
      else if (v > b2) { b2 = v; i2 = j; }
    }
    cs1[t] = b1; cs2[t] = b2; ct1[t] = i1; ct2[t] = i2;
    __syncthreads();
    for (int o = 128; o > 0; o >>= 1) {
      if (t < o) {
        float a1 = cs1[t], a2 = cs2[t];
        int ai1 = ct1[t], ai2 = ct2[t];
        float w1 = cs1[t + o], w2 = cs2[t + o];
        int j1 = ct1[t + o], j2 = ct2[t + o];
        float v1, v2f; int ni1, ni2;
        if (gt_pair(a1, ai1, w1, j1)) {
          v1 = a1; ni1 = ai1;
          if (gt_pair(a2, ai2, w1, j1)) { v2f = a2; ni2 = ai2; }
          else { v2f = w1; ni2 = j1; }
        } else {
          v1 = w1; ni1 = j1;
          if (gt_pair(a1, ai1, w2, j2)) { v2f = a1; ni2 = ai1; }
          else { v2f = w2; ni2 = j2; }
        }
        cs1[t] = v1; ct1[t] = ni1; cs2[t] = v2f; ct2[t] = ni2;
      }
      __syncthreads();
    }
    if (t == 0) {
      colti[2 * m] = ct1[0];
      colti[2 * m + 1] = ct2[0];
    }
  }
  grid.sync();

  // --- gather negatives for this block's rows
  {
    const int d = t & 127;
    const int half = t >> 7;
#pragma unroll 4
    for (int p = 0; p < 32; ++p) {
      const int r = bid * RPB + p * 2 + half;
      const int m = negidx[r];
      const int j1 = colti[2 * m], j2 = colti[2 * m + 1];
      const int j = (j1 != r) ? j1 : j2;
      out[(size_t)(KK * DD) + (size_t)r * DD + d] = E[(size_t)j * DD + d];
    }
  }
}

extern "C" void kernel_launch(void* const* d_in, const int* in_sizes, int n_in,
                              void* d_out, int out_size, void* d_ws, size_t ws_size,
                              hipStream_t stream) {
  const float* E = (const float*)d_in[0];
  const float* C0 = (const float*)d_in[1];
  float* out = (float*)d_out;

  float* wsf = (float*)d_ws;
  float* cb0 = wsf;                               // KK*DD
  float* cb1 = cb0 + KK * DD;                     // KK*DD
  float* updb = cb1 + KK * DD;                    // KK*DD
  float* n2b = updb + KK * DD;                    // KK
  float* partial = n2b + KK;                      // NCHK*KK*DD = 8MB
  float* simT = partial;                          // KK*NN = 4MB (aliased; partial dead)
  int* pcount = (int*)(partial + (size_t)NCHK * KK * DD);  // NCHK*KK
  int* negidx = pcount + NCHK * KK;               // NN
  int* colti = negidx + NN;                       // 2*KK

  void* args[] = {(void*)&E, (void*)&C0, (void*)&out, (void*)&cb0, (void*)&cb1,
                  (void*)&updb, (void*)&n2b, (void*)&partial, (void*)&pcount,
                  (void*)&negidx, (void*)&simT, (void*)&colti};
  hipLaunchCooperativeKernel((const void*)k_mega, dim3(NCHK), dim3(256), args, 0,
                             stream);
}

// Round 4
// 549.640 us; speedup vs baseline: 1.9711x; 1.9711x over previous
//
#include <hip/hip_runtime.h>
#include <float.h>

#define NN 16384
#define DD 128
#define KK 64
#define N_ITERS 10
#define NCHK 256          // fused blocks = row chunks
#define RPB 64            // rows per block
#define CSTR 132          // padded LDS stride (floats): bank shift 4 per row, 16B aligned
#define EPSN 1e-12f
#define TOL2 1e-8f        // (1e-4)^2
#define MOM 0.9f
#define MOM1 0.1f
#define QS 1073741824.0   // 2^30 fixed-point scale
#define IQS (1.0 / 1073741824.0)

typedef unsigned long long ull;

__device__ __forceinline__ bool gt_pair(float v, int i, float w, int j) {
  return (v > w) || (v == w && i < j);
}

// ---- zero the iter-0 accumulator every call (graph replays don't re-poison)
__global__ __launch_bounds__(256) void k_zero(ull* __restrict__ acc0,
                                              int* __restrict__ cnt0) {
  int g = blockIdx.x * 256 + threadIdx.x;
  acc0[g] = 0ull;
  if (g < KK) cnt0[g] = 0;
}

// ---- fused iteration: reconstruct c_t from int64 partials -> conv select ->
//      normalize -> sim/labels -> (FINAL=0: int64 partial atomics | FINAL=1:
//      negidx + per-block per-centroid top2)
template <int FINAL>
__global__ __launch_bounds__(256, 2) void k_fused(
    const float* __restrict__ E, const float* __restrict__ C0,
    float* __restrict__ out,
    const float* __restrict__ cbR, float* __restrict__ cbW,
    const ull* __restrict__ accR, const int* __restrict__ cntR,
    ull* __restrict__ accW, int* __restrict__ cntW,
    ull* __restrict__ accZ, int* __restrict__ cntZ,
    int it,
    int* __restrict__ negidx, float* __restrict__ btv, int* __restrict__ bti) {
  const int t = threadIdx.x;
  const int bid = blockIdx.x;
  __shared__ float csp[KK * CSTR];    // staged raw c -> selected -> normalized
  __shared__ float smem2[KK * CSTR];  // upd | segment acc [m*128+d] | sim tile [r*65+m]
  __shared__ float cinv[KK];
  __shared__ int lab[RPB];
  __shared__ int scnt[KK];
  __shared__ int s_sel;

  // --- zero the (t+1)%3 partial buffers for the next iteration (race-free:
  //     nobody reads/writes that buffer in this kernel)
  if (!FINAL) {
    if (t < 32) accZ[bid * 32 + t] = 0ull;
    if (bid == 0 && t >= 32 && t < 32 + KK) cntZ[t - 32] = 0;
  }
  if (t < KK) scnt[t] = (it == 0) ? 0 : cntR[t];
  __syncthreads();

  // --- phase 1: per-element mean + momentum update (redundant per block)
  for (int e = t; e < KK * DD; e += 256) {
    const int m = e >> 7, d = e & 127;
    float cv, u;
    if (it == 0) {
      cv = C0[e]; u = cv;
    } else {
      cv = cbR[e];
      long long a = (long long)accR[e];
      float s = (float)((double)a * IQS);
      int cnt = scnt[m];
      float mean = (cnt > 0) ? (s / fmaxf((float)cnt, 1.0f)) : cv;
      u = MOM1 * cv + MOM * mean;
    }
    csp[m * CSTR + d] = cv;
    smem2[m * CSTR + d] = u;
  }
  __syncthreads();
  // --- convergence: n2[m] = ||c-upd||^2 (d rotated by t to avoid bank conflicts)
  if (t < KK) {
    float ss = 0.f;
    for (int dj = 0; dj < DD; ++dj) {
      int d = (dj + t) & 127;
      float df = csp[t * CSTR + d] - smem2[t * CSTR + d];
      ss += df * df;
    }
    bool ok = (it == 0) ? true : (ss < TOL2);
    unsigned long long mk = __ballot(ok);
    if (t == 0) s_sel = (mk == ~0ull) ? 1 : 0;
  }
  __syncthreads();
  const int takeC = s_sel;
  // --- select c_t; block 0 materializes globally
  for (int e = t; e < KK * DD; e += 256) {
    const int m = e >> 7, d = e & 127;
    float v = takeC ? csp[m * CSTR + d] : smem2[m * CSTR + d];
    csp[m * CSTR + d] = v;
    if (bid == 0) {
      if (FINAL) out[e] = v;
      else cbW[e] = v;
    }
  }
  __syncthreads();
  // --- normalize centroids in LDS
  if (t < KK) {
    const float4* cm = (const float4*)(csp + t * CSTR);
    float s = 0.f;
#pragma unroll
    for (int q = 0; q < 32; ++q) {
      float4 v = cm[q];
      s += v.x * v.x + v.y * v.y + v.z * v.z + v.w * v.w;
    }
    cinv[t] = 1.0f / fmaxf(sqrtf(s), EPSN);
  }
  __syncthreads();
  for (int e = t; e < KK * DD; e += 256)
    csp[(e >> 7) * CSTR + (e & 127)] *= cinv[e >> 7];
  __syncthreads();

  // --- own row -> registers, normalized (same fp order as rounds 1/2)
  const int row = bid * RPB + (t >> 2);
  const int cg4 = t & 3;
  const int rloc = t >> 2;
  float4 rv[32];
  {
    const float4* rp = (const float4*)(E + (size_t)row * DD);
    float s = 0.f;
#pragma unroll
    for (int q = 0; q < 32; ++q) {
      float4 v = rp[q];
      s += v.x * v.x + v.y * v.y + v.z * v.z + v.w * v.w;
      rv[q] = v;
    }
    float inv = 1.0f / fmaxf(sqrtf(s), EPSN);
#pragma unroll
    for (int q = 0; q < 32; ++q) {
      rv[q].x *= inv; rv[q].y *= inv; rv[q].z *= inv; rv[q].w *= inv;
    }
  }

  // --- sim: 4 lanes/row x 16 centroids each, m interleaved (broadcast, conflict-free)
  float b1 = -3.0e38f, b2 = -3.0e38f;
  int i1 = 0, i2 = 0;
#pragma unroll 4
  for (int mm = 0; mm < 16; ++mm) {
    const int m = mm * 4 + cg4;
    const float4* cp = (const float4*)(csp + m * CSTR);
    float a = 0.f;
#pragma unroll
    for (int q = 0; q < 32; ++q) {
      float4 cv = cp[q];
      a += rv[q].x * cv.x + rv[q].y * cv.y + rv[q].z * cv.z + rv[q].w * cv.w;
    }
    if (FINAL) smem2[rloc * 65 + m] = a;
    if (a > b1) { b2 = b1; i2 = i1; b1 = a; i1 = m; }
    else if (a > b2) { b2 = a; i2 = m; }
  }
  // merge top-2 across the 4 lanes of this row (stable: lower index wins ties)
#pragma unroll
  for (int off = 1; off < 4; off <<= 1) {
    float w1 = __shfl_xor(b1, off);
    float w2 = __shfl_xor(b2, off);
    int j1 = __shfl_xor(i1, off);
    int j2 = __shfl_xor(i2, off);
    float v1, v2f; int ni1, ni2;
    if (gt_pair(b1, i1, w1, j1)) {
      v1 = b1; ni1 = i1;
      if (gt_pair(b2, i2, w1, j1)) { v2f = b2; ni2 = i2; }
      else { v2f = w1; ni2 = j1; }
    } else {
      v1 = w1; ni1 = j1;
      if (gt_pair(b1, i1, w2, j2)) { v2f = b1; ni2 = i1; }
      else { v2f = w2; ni2 = j2; }
    }
    b1 = v1; i1 = ni1; b2 = v2f; i2 = ni2;
  }

  if (!FINAL) {
    if (cg4 == 0) lab[rloc] = i1;
    __syncthreads();
    for (int e = t; e < KK * DD; e += 256) smem2[e] = 0.f;
    __syncthreads();
    // deterministic per-block segment accumulation (ascending row order)
    if (t < 128) {
#pragma unroll 4
      for (int r = 0; r < RPB; ++r)
        smem2[lab[r] * DD + t] += E[(size_t)(bid * RPB + r) * DD + t];
    } else if (t < 192) {
      const int m = t - 128;
      int c = 0;
#pragma unroll
      for (int r = 0; r < RPB; ++r) c += (lab[r] == m) ? 1 : 0;
      if (c > 0) atomicAdd(&cntW[m], c);
    }
    __syncthreads();
    // fixed-point int64 atomics: exactly associative -> order-independent,
    // bit-deterministic across graph replays
    for (int e = t; e < KK * DD; e += 256) {
      float v = smem2[e];
      if (v != 0.f)
        atomicAdd((ull*)&accW[e],
                  (ull)(long long)__double2ll_rn((double)v * QS));
    }
  } else {
    if (cg4 == 0) negidx[row] = i2;
    __syncthreads();
    // per-block per-centroid top-2 rows (ascending row order, first-max wins)
    if (t < KK) {
      const int m = t;
      float c1 = -3.0e38f, c2 = -3.0e38f;
      int j1 = -1, j2 = -1;
      for (int r = 0; r < RPB; ++r) {
        float v = smem2[r * 65 + m];
        int gi = bid * RPB + r;
        if (v > c1) { c2 = c1; j2 = j1; c1 = v; j1 = gi; }
        else if (v > c2) { c2 = v; j2 = gi; }
      }
      btv[(bid * KK + m) * 2 + 0] = c1;
      btv[(bid * KK + m) * 2 + 1] = c2;
      bti[(bid * KK + m) * 2 + 0] = j1;
      bti[(bid * KK + m) * 2 + 1] = j2;
    }
  }
}

// ---- merge 256 per-block top-2 candidates per centroid -> global top-2
__global__ __launch_bounds__(256) void k_top(const float* __restrict__ btv,
                                             const int* __restrict__ bti,
                                             int* __restrict__ colti) {
  const int m = blockIdx.x, t = threadIdx.x;
  float b1 = btv[(t * KK + m) * 2 + 0];
  float b2 = btv[(t * KK + m) * 2 + 1];
  int i1 = bti[(t * KK + m) * 2 + 0];
  int i2 = bti[(t * KK + m) * 2 + 1];
  __shared__ float s1[256], s2[256];
  __shared__ int t1[256], t2[256];
  s1[t] = b1; s2[t] = b2; t1[t] = i1; t2[t] = i2;
  __syncthreads();
  for (int o = 128; o > 0; o >>= 1) {
    if (t < o) {
      float a1 = s1[t], a2 = s2[t];
      int ai1 = t1[t], ai2 = t2[t];
      float w1 = s1[t + o], w2 = s2[t + o];
      int j1 = t1[t + o], j2 = t2[t + o];
      float v1, v2f; int ni1, ni2;
      if (gt_pair(a1, ai1, w1, j1)) {
        v1 = a1; ni1 = ai1;
        if (gt_pair(a2, ai2, w1, j1)) { v2f = a2; ni2 = ai2; }
        else { v2f = w1; ni2 = j1; }
      } else {
        v1 = w1; ni1 = j1;
        if (gt_pair(a1, ai1, w2, j2)) { v2f = a1; ni2 = ai1; }
        else { v2f = w2; ni2 = j2; }
      }
      s1[t] = v1; t1[t] = ni1; s2[t] = v2f; t2[t] = ni2;
    }
    __syncthreads();
  }
  if (t == 0) {
    colti[2 * m] = t1[0];
    colti[2 * m + 1] = t2[0];
  }
}

// ---- gather negatives
__global__ __launch_bounds__(256) void k_gather(const float* __restrict__ E,
                                                const int* __restrict__ negidx,
                                                const int* __restrict__ colti,
                                                float* __restrict__ out) {
#pragma unroll
  for (int k = 0; k < 4; ++k) {
    int idx = (blockIdx.x * 4 + k) * 256 + threadIdx.x;
    int row = idx >> 7, d = idx & 127;
    int m = negidx[row];
    int j1 = colti[2 * m], j2 = colti[2 * m + 1];
    int j = (j1 != row) ? j1 : j2;
    out[(size_t)(KK * DD) + (size_t)row * DD + d] = E[(size_t)j * DD + d];
  }
}

extern "C" void kernel_launch(void* const* d_in, const int* in_sizes, int n_in,
                              void* d_out, int out_size, void* d_ws, size_t ws_size,
                              hipStream_t stream) {
  const float* E = (const float*)d_in[0];
  const float* C0 = (const float*)d_in[1];
  float* out = (float*)d_out;

  ull* acc3 = (ull*)d_ws;                     // 3 * 8192 int64
  int* cnt3 = (int*)(acc3 + 3 * KK * DD);     // 3 * 64
  float* cb0 = (float*)(cnt3 + 3 * KK);       // 8192
  float* cb1 = cb0 + KK * DD;                 // 8192
  float* btv = cb1 + KK * DD;                 // 256*64*2
  int* bti = (int*)(btv + NCHK * KK * 2);     // 256*64*2
  int* negidx = bti + NCHK * KK * 2;          // NN
  int* colti = negidx + NN;                   // 2*KK

  k_zero<<<32, 256, 0, stream>>>(acc3, cnt3);

  for (int it = 0; it <= N_ITERS; ++it) {
    ull* accR = acc3 + ((it + 2) % 3) * (KK * DD);
    ull* accW = acc3 + (it % 3) * (KK * DD);
    ull* accZ = acc3 + ((it + 1) % 3) * (KK * DD);
    int* cntR = cnt3 + ((it + 2) % 3) * KK;
    int* cntW = cnt3 + (it % 3) * KK;
    int* cntZ = cnt3 + ((it + 1) % 3) * KK;
    const float* cbR = (it == 0) ? C0 : ((it & 1) ? cb0 : cb1);
    float* cbW = (it & 1) ? cb1 : cb0;
    if (it < N_ITERS) {
      k_fused<0><<<NCHK, 256, 0, stream>>>(E, C0, out, cbR, cbW, accR, cntR,
                                           accW, cntW, accZ, cntZ, it,
                                           nullptr, nullptr, nullptr);
    } else {
      k_fused<1><<<NCHK, 256, 0, stream>>>(E, C0, out, cbR, nullptr, accR, cntR,
                                           nullptr, nullptr, nullptr, nullptr, it,
                                           negidx, btv, bti);
    }
  }
  k_top<<<KK, 256, 0, stream>>>(btv, bti, colti);
  k_gather<<<NN * DD / 1024, 256, 0, stream>>>(E, negidx, colti, out);
}